// Round 16
// baseline (268.727 us; speedup 1.0000x reference)
//
#include <hip/hip_runtime.h>
#include <hip/hip_bf16.h>

typedef __hip_bfloat16 bf16;
typedef short bf16x8 __attribute__((ext_vector_type(8)));
typedef float f32x4 __attribute__((ext_vector_type(4)));

// B=4, T=2048, D=1024, H=16, HD=64

static __device__ __forceinline__ void glds16(const bf16* g, bf16* l) {
  __builtin_amdgcn_global_load_lds(
      (const __attribute__((address_space(1))) void*)g,
      (__attribute__((address_space(3))) void*)l, 16, 0, 0);
}

static __device__ __forceinline__ unsigned short f2b(float f) {
  return __builtin_bit_cast(unsigned short, __float2bfloat16(f));
}
static __device__ __forceinline__ float b2f(unsigned int u16bits) {
  return __builtin_bit_cast(float, u16bits << 16);
}
static __device__ __forceinline__ float ex2(float x) {
  return __builtin_amdgcn_exp2f(x);
}

// ---------------- fp32 -> bf16 convert, 4 elems/thread ----------------
__global__ void k_convert(const float* __restrict__ in, unsigned short* __restrict__ out, int n4) {
  int i = blockIdx.x * 256 + threadIdx.x;
  if (i >= n4) return;
  float4 v = reinterpret_cast<const float4*>(in)[i];
  ushort4 o;
  o.x = f2b(v.x); o.y = f2b(v.y); o.z = f2b(v.z); o.w = f2b(v.w);
  reinterpret_cast<ushort4*>(out)[i] = o;
}

// ---------------- transpose R x C fp32  ->  C x R bf16 ----------------
__global__ void k_transpose(const float* __restrict__ in, bf16* __restrict__ out, int R, int C) {
  __shared__ float t[32][33];
  int c0 = blockIdx.x * 32, r0 = blockIdx.y * 32;
  int tx = threadIdx.x, ty = threadIdx.y;  // block (32,8)
  #pragma unroll
  for (int j = 0; j < 32; j += 8)
    t[ty + j][tx] = in[(size_t)(r0 + ty + j) * C + c0 + tx];
  __syncthreads();
  #pragma unroll
  for (int j = 0; j < 32; j += 8)
    out[(size_t)(c0 + ty + j) * R + r0 + tx] = __float2bfloat16(t[tx][ty + j]);
}

// ============ QKV GEMM: 256x256 tile, BK=64, 8-phase counted-vmcnt ============
// 512 thr = 8 waves (wr=wv>>2 in {0,1}, wc=wv&3 in {0..3}); per-wave C 128x64.
// LDS 128KB dynamic: 2 buffers x (A 256x64 + B 256x64) bf16 (no pointer
// arrays into LDS -- R15 compile lesson: addrspacecast static init rejected).
// Half-iter h computes K-tile h from buf[h&1] in 4 phases (2 row-frags x 4
// col-frags x K=64 = 16 MFMA each); B-frags read once at pi0 (regs).
// Staging (2 glds/wave/phase) into regions dead since an earlier barrier:
//   pi0: A calls c1,c3 of tile h+1 -> buf[h+1]   (dead after prev pi2/pi3)
//   pi1: B c0,c1 of tile h+2 -> buf[h]           (B dead after pi0)
//   pi2: B c2,c3    "
//   pi3: A c0,c2    "                            (rows p0,p1 dead pi0/pi1)
// vmcnt(6) ONLY at pi3 (leaves pi1-3's 6 calls in flight). Raw s_barrier
// (no __syncthreads vmcnt(0) drain). lgkmcnt(0)+sched_barrier before MFMA.
__global__ __launch_bounds__(512, 1)
void k_gemm2(const bf16* __restrict__ A, const bf16* __restrict__ Bt,
             const float* __restrict__ bias,
             bf16* __restrict__ Qh, bf16* __restrict__ Kh, bf16* __restrict__ Vt)
{
  constexpr int K = 1024, NT = 16;     // K / 64
  extern __shared__ bf16 sm[];
  #define BUFA(bb) (sm + (bb) * 2 * 16384)
  #define BUFB(bb) (sm + (bb) * 2 * 16384 + 16384)

  const int tid = threadIdx.x;
  const int wv = tid >> 6, lane = tid & 63;
  const int wr = wv >> 2, wc = wv & 3;
  const int l4 = lane >> 4, l15 = lane & 15;

  // XCD swizzle: 384 blocks (48/XCD), bijective since 384 % 8 == 0
  const int flat = blockIdx.x;
  const int swz = (flat & 7) * 48 + (flat >> 3);
  const int bx = swz % 12;             // N blocks (3072/256)
  const int by = swz / 12;             // M blocks (8192/256)

  // staging: one glds call = 64 lanes x 16B = 8 rows x 64 cols
  const int srow = lane >> 3;          // 0..7
  const int sgran = (lane & 7) ^ srow; // pre-swizzled source granule (row&7 == srow)
  const bf16* gA = A  + (size_t)(by * 256 + wv * 8 + srow) * K + sgran * 8;
  const bf16* gB = Bt + (size_t)(bx * 256 + wv * 8 + srow) * K + sgran * 8;

  f32x4 acc[8][4];
  #pragma unroll
  for (int i = 0; i < 8; ++i)
    #pragma unroll
    for (int j = 0; j < 4; ++j) acc[i][j] = f32x4{0.f, 0.f, 0.f, 0.f};

  #define STAGE_A(t, c, bb) glds16(gA + (size_t)((c) * 64) * K + (t) * 64, BUFA(bb) + ((c) * 64 + wv * 8) * 64)
  #define STAGE_B(t, c, bb) glds16(gB + (size_t)((c) * 64) * K + (t) * 64, BUFB(bb) + ((c) * 64 + wv * 8) * 64)

  // prologue: tile0 -> buf0 (8 calls), tile1 -> buf1 (B all + A c0,c2 = 6 calls)
  #pragma unroll
  for (int c = 0; c < 4; ++c) STAGE_A(0, c, 0);
  #pragma unroll
  for (int c = 0; c < 4; ++c) STAGE_B(0, c, 0);
  #pragma unroll
  for (int c = 0; c < 4; ++c) STAGE_B(1, c, 1);
  STAGE_A(1, 0, 1);
  STAGE_A(1, 2, 1);
  asm volatile("s_waitcnt vmcnt(6)");
  __builtin_amdgcn_sched_barrier(0);
  __builtin_amdgcn_s_barrier();
  __builtin_amdgcn_sched_barrier(0);

  for (int h = 0; h < NT; ++h) {
    const int b = h & 1;
    bf16x8 bfr[4][2];
    #pragma unroll
    for (int p = 0; p < 4; ++p) {
      // ---- ds_read register subtile ----
      if (p == 0) {
        #pragma unroll
        for (int j = 0; j < 4; ++j)
          #pragma unroll
          for (int kh = 0; kh < 2; ++kh) {
            const int R = wc * 64 + j * 16 + l15;
            bfr[j][kh] = *reinterpret_cast<const bf16x8*>(
                BUFB(b) + R * 64 + (((kh * 4 + l4) ^ (R & 7)) * 8));
          }
      }
      bf16x8 af[2][2];
      #pragma unroll
      for (int ii = 0; ii < 2; ++ii)
        #pragma unroll
        for (int kh = 0; kh < 2; ++kh) {
          const int R = wr * 128 + p * 32 + ii * 16 + l15;
          af[ii][kh] = *reinterpret_cast<const bf16x8*>(
              BUFA(b) + R * 64 + (((kh * 4 + l4) ^ (R & 7)) * 8));
        }
      // ---- stage 2 calls into dead regions ----
      if (p == 0) { if (h + 1 < NT) { STAGE_A(h + 1, 1, b ^ 1); STAGE_A(h + 1, 3, b ^ 1); } }
      if (p == 1) { if (h + 2 < NT) { STAGE_B(h + 2, 0, b);     STAGE_B(h + 2, 1, b);     } }
      if (p == 2) { if (h + 2 < NT) { STAGE_B(h + 2, 2, b);     STAGE_B(h + 2, 3, b);     } }
      if (p == 3) { if (h + 2 < NT) { STAGE_A(h + 2, 0, b);     STAGE_A(h + 2, 2, b);     } }
      __builtin_amdgcn_s_barrier();
      __builtin_amdgcn_sched_barrier(0);
      asm volatile("s_waitcnt lgkmcnt(0)");
      __builtin_amdgcn_sched_barrier(0);
      __builtin_amdgcn_s_setprio(1);
      #pragma unroll
      for (int ii = 0; ii < 2; ++ii)
        #pragma unroll
        for (int j = 0; j < 4; ++j) {
          acc[p * 2 + ii][j] = __builtin_amdgcn_mfma_f32_16x16x32_bf16(af[ii][0], bfr[j][0], acc[p * 2 + ii][j], 0, 0, 0);
          acc[p * 2 + ii][j] = __builtin_amdgcn_mfma_f32_16x16x32_bf16(af[ii][1], bfr[j][1], acc[p * 2 + ii][j], 0, 0, 0);
        }
      __builtin_amdgcn_s_setprio(0);
      if (p == 3) {
        if (h < NT - 2) asm volatile("s_waitcnt vmcnt(6)");
        else            asm volatile("s_waitcnt vmcnt(0)");
        __builtin_amdgcn_sched_barrier(0);
      }
      __builtin_amdgcn_s_barrier();
      __builtin_amdgcn_sched_barrier(0);
    }
  }
  #undef STAGE_A
  #undef STAGE_B
  #undef BUFA
  #undef BUFB

  // epilogue: scatter to Qh/Kh/Vt (+bias; Q pre-scaled into exp2 domain)
  #pragma unroll
  for (int j = 0; j < 4; ++j) {
    const int n = bx * 256 + wc * 64 + j * 16 + l15;
    const float bj = bias[n];
    const int s = n >> 10;
    const int hh = (n >> 6) & 15;
    const int d = n & 63;
    #pragma unroll
    for (int i = 0; i < 8; ++i) {
      #pragma unroll
      for (int r = 0; r < 4; ++r) {
        const int m = by * 256 + wr * 128 + i * 16 + l4 * 4 + r;
        const int bb = m >> 11, t = m & 2047;
        float of = acc[i][j][r] + bj;
        if (s == 0) of *= 0.18033688f;  // 1/8 * log2(e)
        const bf16 o = __float2bfloat16(of);
        if (s == 0)      Qh[((size_t)((bb * 16 + hh) * 2048 + t)) * 64 + d] = o;
        else if (s == 1) Kh[((size_t)((bb * 16 + hh) * 2048 + t)) * 64 + d] = o;
        else             Vt[((size_t)((bb * 16 + hh) * 64 + d)) * 2048 + t] = o;
      }
    }
  }
}

// ---------------- FC GEMM (R14-proven): 128x128, BK=64, swizzled LDS ----------------
__global__ __launch_bounds__(256, 2)
void k_gemm_fc(const bf16* __restrict__ A, const bf16* __restrict__ Bt,
               const float* __restrict__ bias, float* __restrict__ Out)
{
  constexpr int K = 1024;
  __shared__ bf16 sA[128 * 64];
  __shared__ bf16 sB[128 * 64];
  const int tid = threadIdx.x;
  const int wv = tid >> 6, lane = tid & 63;
  const int wr = wv >> 1, wc = wv & 1;
  const int l4 = lane >> 4, l15 = lane & 15;

  const int nbx = gridDim.x;
  const int nwg = nbx * gridDim.y;
  const int flat = blockIdx.y * nbx + blockIdx.x;
  const int cpx = nwg >> 3;
  const int swz = (flat & 7) * cpx + (flat >> 3);
  const int bx = swz % nbx;
  const int by = swz / nbx;

  const int srow8 = lane >> 3;
  const int sgran = (lane & 7) ^ srow8;
  const bf16* gA0 = A  + (size_t)(by * 128 + wv * 8 + srow8) * K + sgran * 8;
  const bf16* gB0 = Bt + (size_t)(bx * 128 + wv * 8 + srow8) * K + sgran * 8;
  bf16* lA0 = sA + wv * 8 * 64;
  bf16* lB0 = sB + wv * 8 * 64;

  f32x4 acc[4][4];
  #pragma unroll
  for (int i = 0; i < 4; ++i)
    #pragma unroll
    for (int j = 0; j < 4; ++j) acc[i][j] = f32x4{0.f, 0.f, 0.f, 0.f};

  for (int kb = 0; kb < K; kb += 64) {
    #pragma unroll
    for (int c = 0; c < 4; ++c) {
      glds16(gA0 + kb + (size_t)(c * 32) * K, lA0 + c * 32 * 64);
      glds16(gB0 + kb + (size_t)(c * 32) * K, lB0 + c * 32 * 64);
    }
    __syncthreads();
    #pragma unroll
    for (int kk = 0; kk < 2; ++kk) {
      bf16x8 af[4], bfr[4];
      #pragma unroll
      for (int i = 0; i < 4; ++i) {
        const int R = wr * 64 + i * 16 + l15;
        af[i] = *reinterpret_cast<const bf16x8*>(sA + R * 64 + (((kk * 4 + l4) ^ (R & 7)) * 8));
      }
      #pragma unroll
      for (int j = 0; j < 4; ++j) {
        const int R = wc * 64 + j * 16 + l15;
        bfr[j] = *reinterpret_cast<const bf16x8*>(sB + R * 64 + (((kk * 4 + l4) ^ (R & 7)) * 8));
      }
      #pragma unroll
      for (int i = 0; i < 4; ++i)
        #pragma unroll
        for (int j = 0; j < 4; ++j)
          acc[i][j] = __builtin_amdgcn_mfma_f32_16x16x32_bf16(af[i], bfr[j], acc[i][j], 0, 0, 0);
    }
    __syncthreads();
  }

  #pragma unroll
  for (int j = 0; j < 4; ++j) {
    const int n = bx * 128 + wc * 64 + j * 16 + l15;
    const float bj = bias[n];
    #pragma unroll
    for (int i = 0; i < 4; ++i)
      #pragma unroll
      for (int r = 0; r < 4; ++r) {
        const int m = by * 128 + wr * 64 + i * 16 + l4 * 4 + r;
        Out[(size_t)m * 1024 + n] = acc[i][j][r] + bj;
      }
  }
}

// ---------------- flash attention (causal), head-major inputs ----------------
// R10/R14-proven version (145 us). 2048 blocks, 4 waves; q-tile pair (g,63-g),
// even/odd kt split, KT=32, swapped QK^T lane-local softmax, defer-max THR=8.
__global__ __launch_bounds__(256, 3)
void k_attn(const bf16* __restrict__ Qh, const bf16* __restrict__ Kh,
            const bf16* __restrict__ Vt, bf16* __restrict__ Ao)
{
  __shared__ unsigned int smem[4608];
  const int tid = threadIdx.x;
  const int wv = tid >> 6, lane = tid & 63;
  const int l4 = lane >> 4, l15 = lane & 15;

  const int bid = blockIdx.x;
  const int xcd = bid & 7;
  const int idx = bid >> 3;
  const int g   = idx & 31;
  const int grp = idx >> 5;
  const int bh  = grp * 8 + xcd;
  const int b = bh >> 4, h = bh & 15;

  const int role = (wv + bid) & 3;
  const int qi = (role < 2) ? g : (63 - g);
  const int parity = role & 1;
  const int qbase = qi * 32;

  const bf16* Qp = Qh + (size_t)bh * 2048 * 64;
  const bf16* Kp = Kh + (size_t)bh * 2048 * 64;
  const bf16* Vp = Vt + (size_t)bh * 64 * 2048;
  bf16* Pw = (bf16*)smem + wv * (32 * 40);

  bf16x8 qa[2][2];
  #pragma unroll
  for (int i = 0; i < 2; ++i)
    #pragma unroll
    for (int kh = 0; kh < 2; ++kh)
      qa[i][kh] = *reinterpret_cast<const bf16x8*>(
          Qp + (size_t)(qbase + i * 16 + l15) * 64 + kh * 32 + l4 * 8);

  f32x4 o[2][4];
  float mr[2], lr[2];
  #pragma unroll
  for (int i = 0; i < 2; ++i) {
    #pragma unroll
    for (int jd = 0; jd < 4; ++jd) o[i][jd] = f32x4{0.f, 0.f, 0.f, 0.f};
    mr[i] = -1e30f; lr[i] = 0.f;
  }

  const int ktmax = (qbase + 31) >> 5;

  const int kt0 = (parity <= ktmax) ? parity : ktmax;
  bf16x8 kbf[2][2];
  #pragma unroll
  for (int j = 0; j < 2; ++j)
    #pragma unroll
    for (int kh = 0; kh < 2; ++kh)
      kbf[j][kh] = *reinterpret_cast<const bf16x8*>(
          Kp + (size_t)(kt0 * 32 + j * 16 + l15) * 64 + kh * 32 + l4 * 8);

  for (int kt = parity; kt <= ktmax; kt += 2) {
    const bool full = (kt * 32 + 31) <= qbase;

    f32x4 s[2][2];
    #pragma unroll
    for (int i = 0; i < 2; ++i)
      #pragma unroll
      for (int j = 0; j < 2; ++j) s[i][j] = f32x4{0.f, 0.f, 0.f, 0.f};
    #pragma unroll
    for (int j = 0; j < 2; ++j)
      #pragma unroll
      for (int i = 0; i < 2; ++i) {
        s[i][j] = __builtin_amdgcn_mfma_f32_16x16x32_bf16(kbf[j][0], qa[i][0], s[i][j], 0, 0, 0);
        s[i][j] = __builtin_amdgcn_mfma_f32_16x16x32_bf16(kbf[j][1], qa[i][1], s[i][j], 0, 0, 0);
      }

    bf16x8 vbf[4];
    #pragma unroll
    for (int jd = 0; jd < 4; ++jd)
      vbf[jd] = *reinterpret_cast<const bf16x8*>(
          Vp + (size_t)(jd * 16 + l15) * 2048 + kt * 32 + l4 * 8);

    #pragma unroll
    for (int i = 0; i < 2; ++i) {
      const int q = qbase + i * 16 + l15;
      #pragma unroll
      for (int j = 0; j < 2; ++j)
        #pragma unroll
        for (int r = 0; r < 4; ++r) {
          float v = s[i][j][r];
          if (!full) {
            const int kk = kt * 32 + j * 16 + l4 * 4 + r;
            if (kk > q) v = -1e30f;
          }
          s[i][j][r] = v;
        }
    }

    #pragma unroll
    for (int i = 0; i < 2; ++i) {
      float mx = s[i][0][0];
      #pragma unroll
      for (int j = 0; j < 2; ++j)
        #pragma unroll
        for (int r = 0; r < 4; ++r)
          if (j + r > 0) mx = fmaxf(mx, s[i][j][r]);
      mx = fmaxf(mx, __shfl_xor(mx, 16));
      mx = fmaxf(mx, __shfl_xor(mx, 32));
      if (__any(mx > mr[i] + 8.f)) {
        const float mn = fmaxf(mr[i], mx);
        const float al = ex2(mr[i] - mn);
        mr[i] = mn;
        lr[i] *= al;
        float albc[4];
        #pragma unroll
        for (int r = 0; r < 4; ++r) albc[r] = __shfl(al, l4 * 4 + r);
        #pragma unroll
        for (int jd = 0; jd < 4; ++jd)
          #pragma unroll
          for (int r = 0; r < 4; ++r) o[i][jd][r] *= albc[r];
      }
      float ps = 0.f;
      #pragma unroll
      for (int j = 0; j < 2; ++j) {
        const float p0 = ex2(s[i][j][0] - mr[i]);
        const float p1 = ex2(s[i][j][1] - mr[i]);
        const float p2 = ex2(s[i][j][2] - mr[i]);
        const float p3 = ex2(s[i][j][3] - mr[i]);
        ps += (p0 + p1) + (p2 + p3);
        const unsigned int u0 = (unsigned int)f2b(p0) | ((unsigned int)f2b(p1) << 16);
        const unsigned int u1 = (unsigned int)f2b(p2) | ((unsigned int)f2b(p3) << 16);
        *reinterpret_cast<uint2*>(Pw + (i * 16 + l15) * 40 + j * 16 + l4 * 4) =
            make_uint2(u0, u1);
      }
      ps += __shfl_xor(ps, 16);
      ps += __shfl_xor(ps, 32);
      lr[i] += ps;
    }

    const int ktn = (kt + 2 <= ktmax) ? (kt + 2) : ktmax;
    #pragma unroll
    for (int j = 0; j < 2; ++j)
      #pragma unroll
      for (int kh = 0; kh < 2; ++kh)
        kbf[j][kh] = *reinterpret_cast<const bf16x8*>(
            Kp + (size_t)(ktn * 32 + j * 16 + l15) * 64 + kh * 32 + l4 * 8);

    bf16x8 pa[2];
    #pragma unroll
    for (int i = 0; i < 2; ++i)
      pa[i] = *reinterpret_cast<const bf16x8*>(Pw + (i * 16 + l15) * 40 + l4 * 8);
    #pragma unroll
    for (int jd = 0; jd < 4; ++jd)
      #pragma unroll
      for (int i = 0; i < 2; ++i)
        o[i][jd] = __builtin_amdgcn_mfma_f32_16x16x32_bf16(pa[i], vbf[jd], o[i][jd], 0, 0, 0);
  }

  float mrv[2][4], lrv[2][4];
  #pragma unroll
  for (int i = 0; i < 2; ++i)
    #pragma unroll
    for (int r = 0; r < 4; ++r) {
      mrv[i][r] = __shfl(mr[i], l4 * 4 + r);
      lrv[i][r] = __shfl(lr[i], l4 * 4 + r);
    }

  __syncthreads();
  unsigned int* reg0 = smem;
  unsigned int* reg1 = smem + 64 * 33;
  if (parity == 1) {
    unsigned int* p = ((role == 1) ? reg0 : reg1) + lane * 33;
    #pragma unroll
    for (int i = 0; i < 2; ++i)
      #pragma unroll
      for (int r = 0; r < 4; ++r) {
        p[i * 4 + r]     = __builtin_bit_cast(unsigned int, mrv[i][r]);
        p[8 + i * 4 + r] = __builtin_bit_cast(unsigned int, lrv[i][r]);
      }
    #pragma unroll
    for (int i = 0; i < 2; ++i)
      #pragma unroll
      for (int jd = 0; jd < 4; ++jd)
        #pragma unroll
        for (int rp = 0; rp < 2; ++rp) {
          unsigned int lo = f2b(o[i][jd][2 * rp]);
          unsigned int hi = f2b(o[i][jd][2 * rp + 1]);
          p[16 + (i * 4 + jd) * 2 + rp] = lo | (hi << 16);
        }
  }
  __syncthreads();
  if (parity == 0) {
    const unsigned int* p = ((role == 0) ? reg0 : reg1) + lane * 33;
    #pragma unroll
    for (int i = 0; i < 2; ++i)
      #pragma unroll
      for (int r = 0; r < 4; ++r) {
        const float m1 = __builtin_bit_cast(float, p[i * 4 + r]);
        const float l1 = __builtin_bit_cast(float, p[8 + i * 4 + r]);
        const float mm = fmaxf(mrv[i][r], m1);
        const float a0 = ex2(mrv[i][r] - mm);
        const float a1 = ex2(m1 - mm);
        const float inv = 1.f / (lrv[i][r] * a0 + l1 * a1);
        const int q = qbase + i * 16 + l4 * 4 + r;
        #pragma unroll
        for (int jd = 0; jd < 4; ++jd) {
          const unsigned int u = p[16 + (i * 4 + jd) * 2 + (r >> 1)];
          const float o1 = b2f((r & 1) ? (u >> 16) : (u & 0xffffu));
          const float val = (o[i][jd][r] * a0 + o1 * a1) * inv;
          Ao[(size_t)(b * 2048 + q) * 1024 + h * 64 + jd * 16 + l15] = __float2bfloat16(val);
        }
      }
  }
}

extern "C" void kernel_launch(void* const* d_in, const int* in_sizes, int n_in,
                              void* d_out, int out_size, void* d_ws, size_t ws_size,
                              hipStream_t stream)
{
  const float* x     = (const float*)d_in[0];
  const float* W_qkv = (const float*)d_in[1];
  const float* b_qkv = (const float*)d_in[2];
  const float* W_fc  = (const float*)d_in[3];
  const float* b_fc  = (const float*)d_in[4];
  float* out = (float*)d_out;

  char* ws = (char*)d_ws;
  bf16* x_bf = (bf16*)ws;  ws += (size_t)8192 * 1024 * 2;            // 16 MB
  bf16* Wqt  = (bf16*)ws;  ws += (size_t)3072 * 1024 * 2;            //  6 MB
  bf16* Wft  = (bf16*)ws;  ws += (size_t)1024 * 1024 * 2;            //  2 MB
  bf16* Qh   = (bf16*)ws;  ws += (size_t)4 * 16 * 2048 * 64 * 2;     // 16 MB
  bf16* Kh   = (bf16*)ws;  ws += (size_t)4 * 16 * 2048 * 64 * 2;     // 16 MB
  bf16* Vt   = (bf16*)ws;  ws += (size_t)4 * 16 * 64 * 2048 * 2;     // 16 MB
  bf16* Ao   = (bf16*)ws;  ws += (size_t)8192 * 1024 * 2;            // 16 MB  (total 88 MB)

  // allow 128KB dynamic LDS for the 8-phase GEMM (idempotent; ignore error)
  (void)hipFuncSetAttribute((const void*)k_gemm2,
                            hipFuncAttributeMaxDynamicSharedMemorySize, 131072);

  k_convert<<<8192, 256, 0, stream>>>(x, (unsigned short*)x_bf, 8192 * 1024 / 4);
  k_transpose<<<dim3(3072 / 32, 1024 / 32), dim3(32, 8), 0, stream>>>(W_qkv, Wqt, 1024, 3072);
  k_transpose<<<dim3(1024 / 32, 1024 / 32), dim3(32, 8), 0, stream>>>(W_fc, Wft, 1024, 1024);
  k_gemm2<<<384, 512, 131072, stream>>>(x_bf, Wqt, b_qkv, Qh, Kh, Vt);
  k_attn<<<2048, 256, 0, stream>>>(Qh, Kh, Vt, Ao);
  k_gemm_fc<<<dim3(8, 64), 256, 0, stream>>>(Ao, Wft, b_fc, out);
}

// Round 17
// 263.458 us; speedup vs baseline: 1.0200x; 1.0200x over previous
//
#include <hip/hip_runtime.h>
#include <hip/hip_bf16.h>

typedef __hip_bfloat16 bf16;
typedef short bf16x8 __attribute__((ext_vector_type(8)));
typedef float f32x4 __attribute__((ext_vector_type(4)));

// B=4, T=2048, D=1024, H=16, HD=64

static __device__ __forceinline__ void glds16(const bf16* g, bf16* l) {
  __builtin_amdgcn_global_load_lds(
      (const __attribute__((address_space(1))) void*)g,
      (__attribute__((address_space(3))) void*)l, 16, 0, 0);
}

static __device__ __forceinline__ unsigned short f2b(float f) {
  return __builtin_bit_cast(unsigned short, __float2bfloat16(f));
}
static __device__ __forceinline__ float b2f(unsigned int u16bits) {
  return __builtin_bit_cast(float, u16bits << 16);
}
static __device__ __forceinline__ float ex2(float x) {
  return __builtin_amdgcn_exp2f(x);
}

// ---------------- fp32 -> bf16 convert, 4 elems/thread ----------------
__global__ void k_convert(const float* __restrict__ in, unsigned short* __restrict__ out, int n4) {
  int i = blockIdx.x * 256 + threadIdx.x;
  if (i >= n4) return;
  float4 v = reinterpret_cast<const float4*>(in)[i];
  ushort4 o;
  o.x = f2b(v.x); o.y = f2b(v.y); o.z = f2b(v.z); o.w = f2b(v.w);
  reinterpret_cast<ushort4*>(out)[i] = o;
}

// ---------------- transpose R x C fp32  ->  C x R bf16 ----------------
__global__ void k_transpose(const float* __restrict__ in, bf16* __restrict__ out, int R, int C) {
  __shared__ float t[32][33];
  int c0 = blockIdx.x * 32, r0 = blockIdx.y * 32;
  int tx = threadIdx.x, ty = threadIdx.y;  // block (32,8)
  #pragma unroll
  for (int j = 0; j < 32; j += 8)
    t[ty + j][tx] = in[(size_t)(r0 + ty + j) * C + c0 + tx];
  __syncthreads();
  #pragma unroll
  for (int j = 0; j < 32; j += 8)
    out[(size_t)(c0 + ty + j) * R + r0 + tx] = __float2bfloat16(t[tx][ty + j]);
}

// ========= QKV GEMM: 256x192 tile, BK=64, 8-phase counted-vmcnt =========
// R16 lesson: 256x256 -> grid 384 = 1.5 cohorts at 1 block/CU (128KB LDS),
// 75% CU-time utilization ate the schedule gain. BN=192 -> grid 32x16=512 =
// exactly 2.0 FULL cohorts; per-block work 0.75x -> makespan 1.5T vs 2T.
// 512 thr = 8 waves (wr=wv>>2 in {0,1}, wc=wv&3); per-wave C 128x48.
// LDS 112KB dynamic: 2 buf x (A 256x64 + B 192x64) bf16.
// Staging per half-iter (A=4 calls, B=3 calls, 64 rows/call):
//   pi0: A(h+1) c1,c3 -> buf b^1   (dead since iter h-1)
//   pi1: B(h+2) c0,c1 -> buf b     (B fully read at pi0)
//   pi2: B(h+2) c2    -> buf b
//   pi3: A(h+2) c0,c2 -> buf b     (pi3 reads rows 96-127/224-255; no overlap)
// vmcnt(5) at pi3 (drains pi0's 2 -> tile h+1 complete; leaves h+2's 5).
__global__ __launch_bounds__(512, 1)
void k_gemm2(const bf16* __restrict__ A, const bf16* __restrict__ Bt,
             const float* __restrict__ bias,
             bf16* __restrict__ Qh, bf16* __restrict__ Kh, bf16* __restrict__ Vt)
{
  constexpr int K = 1024, NT = 16;     // K / 64
  extern __shared__ bf16 sm[];
  #define BUFA(bb) (sm + (bb) * 28672)
  #define BUFB(bb) (sm + (bb) * 28672 + 16384)

  const int tid = threadIdx.x;
  const int wv = tid >> 6, lane = tid & 63;
  const int wr = wv >> 2, wc = wv & 3;
  const int l4 = lane >> 4, l15 = lane & 15;

  // XCD swizzle: 512 blocks (64/XCD), bijective since 512 % 8 == 0
  const int flat = blockIdx.x;
  const int swz = (flat & 7) * 64 + (flat >> 3);
  const int bx = swz % 16;             // N blocks (3072/192)
  const int by = swz / 16;             // M blocks (8192/256)

  // staging: one glds call = 8 waves x 8 rows = 64 rows x 64 cols
  const int srow = lane >> 3;          // 0..7
  const int sgran = (lane & 7) ^ srow; // pre-swizzled source granule (row&7 == srow)
  const bf16* gA = A  + (size_t)(by * 256 + wv * 8 + srow) * K + sgran * 8;
  const bf16* gB = Bt + (size_t)(bx * 192 + wv * 8 + srow) * K + sgran * 8;

  f32x4 acc[8][3];
  #pragma unroll
  for (int i = 0; i < 8; ++i)
    #pragma unroll
    for (int j = 0; j < 3; ++j) acc[i][j] = f32x4{0.f, 0.f, 0.f, 0.f};

  #define STAGE_A(t, c, bb) glds16(gA + (size_t)((c) * 64) * K + (t) * 64, BUFA(bb) + ((c) * 64 + wv * 8) * 64)
  #define STAGE_B(t, c, bb) glds16(gB + (size_t)((c) * 64) * K + (t) * 64, BUFB(bb) + ((c) * 64 + wv * 8) * 64)

  // prologue: tile0 -> buf0 (A4+B3=7), tile1 -> buf1 (B3 + A c0,c2 = 5)
  #pragma unroll
  for (int c = 0; c < 4; ++c) STAGE_A(0, c, 0);
  #pragma unroll
  for (int c = 0; c < 3; ++c) STAGE_B(0, c, 0);
  #pragma unroll
  for (int c = 0; c < 3; ++c) STAGE_B(1, c, 1);
  STAGE_A(1, 0, 1);
  STAGE_A(1, 2, 1);
  asm volatile("s_waitcnt vmcnt(5)");
  __builtin_amdgcn_sched_barrier(0);
  __builtin_amdgcn_s_barrier();
  __builtin_amdgcn_sched_barrier(0);

  for (int h = 0; h < NT; ++h) {
    const int b = h & 1;
    bf16x8 bfr[3][2];
    #pragma unroll
    for (int p = 0; p < 4; ++p) {
      // ---- ds_read register subtile ----
      if (p == 0) {
        #pragma unroll
        for (int j = 0; j < 3; ++j)
          #pragma unroll
          for (int kh = 0; kh < 2; ++kh) {
            const int R = wc * 48 + j * 16 + l15;
            bfr[j][kh] = *reinterpret_cast<const bf16x8*>(
                BUFB(b) + R * 64 + (((kh * 4 + l4) ^ (R & 7)) * 8));
          }
      }
      bf16x8 af[2][2];
      #pragma unroll
      for (int ii = 0; ii < 2; ++ii)
        #pragma unroll
        for (int kh = 0; kh < 2; ++kh) {
          const int R = wr * 128 + p * 32 + ii * 16 + l15;
          af[ii][kh] = *reinterpret_cast<const bf16x8*>(
              BUFA(b) + R * 64 + (((kh * 4 + l4) ^ (R & 7)) * 8));
        }
      // ---- stage calls into dead regions ----
      if (p == 0) { if (h + 1 < NT) { STAGE_A(h + 1, 1, b ^ 1); STAGE_A(h + 1, 3, b ^ 1); } }
      if (p == 1) { if (h + 2 < NT) { STAGE_B(h + 2, 0, b);     STAGE_B(h + 2, 1, b);     } }
      if (p == 2) { if (h + 2 < NT) { STAGE_B(h + 2, 2, b);     } }
      if (p == 3) { if (h + 2 < NT) { STAGE_A(h + 2, 0, b);     STAGE_A(h + 2, 2, b);     } }
      __builtin_amdgcn_s_barrier();
      __builtin_amdgcn_sched_barrier(0);
      asm volatile("s_waitcnt lgkmcnt(0)");
      __builtin_amdgcn_sched_barrier(0);
      __builtin_amdgcn_s_setprio(1);
      #pragma unroll
      for (int ii = 0; ii < 2; ++ii)
        #pragma unroll
        for (int j = 0; j < 3; ++j) {
          acc[p * 2 + ii][j] = __builtin_amdgcn_mfma_f32_16x16x32_bf16(af[ii][0], bfr[j][0], acc[p * 2 + ii][j], 0, 0, 0);
          acc[p * 2 + ii][j] = __builtin_amdgcn_mfma_f32_16x16x32_bf16(af[ii][1], bfr[j][1], acc[p * 2 + ii][j], 0, 0, 0);
        }
      __builtin_amdgcn_s_setprio(0);
      if (p == 3) {
        if (h < NT - 2) asm volatile("s_waitcnt vmcnt(5)");
        else            asm volatile("s_waitcnt vmcnt(0)");
        __builtin_amdgcn_sched_barrier(0);
      }
      __builtin_amdgcn_s_barrier();
      __builtin_amdgcn_sched_barrier(0);
    }
  }
  #undef STAGE_A
  #undef STAGE_B
  #undef BUFA
  #undef BUFB

  // epilogue: scatter to Qh/Kh/Vt (+bias; Q pre-scaled into exp2 domain)
  #pragma unroll
  for (int j = 0; j < 3; ++j) {
    const int n = bx * 192 + wc * 48 + j * 16 + l15;
    const float bj = bias[n];
    const int s = n >> 10;
    const int hh = (n >> 6) & 15;
    const int d = n & 63;
    #pragma unroll
    for (int i = 0; i < 8; ++i) {
      #pragma unroll
      for (int r = 0; r < 4; ++r) {
        const int m = by * 256 + wr * 128 + i * 16 + l4 * 4 + r;
        const int bb = m >> 11, t = m & 2047;
        float of = acc[i][j][r] + bj;
        if (s == 0) of *= 0.18033688f;  // 1/8 * log2(e)
        const bf16 o = __float2bfloat16(of);
        if (s == 0)      Qh[((size_t)((bb * 16 + hh) * 2048 + t)) * 64 + d] = o;
        else if (s == 1) Kh[((size_t)((bb * 16 + hh) * 2048 + t)) * 64 + d] = o;
        else             Vt[((size_t)((bb * 16 + hh) * 64 + d)) * 2048 + t] = o;
      }
    }
  }
}

// ---------------- FC GEMM (R14-proven): 128x128, BK=64, swizzled LDS ----------------
__global__ __launch_bounds__(256, 2)
void k_gemm_fc(const bf16* __restrict__ A, const bf16* __restrict__ Bt,
               const float* __restrict__ bias, float* __restrict__ Out)
{
  constexpr int K = 1024;
  __shared__ bf16 sA[128 * 64];
  __shared__ bf16 sB[128 * 64];
  const int tid = threadIdx.x;
  const int wv = tid >> 6, lane = tid & 63;
  const int wr = wv >> 1, wc = wv & 1;
  const int l4 = lane >> 4, l15 = lane & 15;

  const int nbx = gridDim.x;
  const int nwg = nbx * gridDim.y;
  const int flat = blockIdx.y * nbx + blockIdx.x;
  const int cpx = nwg >> 3;
  const int swz = (flat & 7) * cpx + (flat >> 3);
  const int bx = swz % nbx;
  const int by = swz / nbx;

  const int srow8 = lane >> 3;
  const int sgran = (lane & 7) ^ srow8;
  const bf16* gA0 = A  + (size_t)(by * 128 + wv * 8 + srow8) * K + sgran * 8;
  const bf16* gB0 = Bt + (size_t)(bx * 128 + wv * 8 + srow8) * K + sgran * 8;
  bf16* lA0 = sA + wv * 8 * 64;
  bf16* lB0 = sB + wv * 8 * 64;

  f32x4 acc[4][4];
  #pragma unroll
  for (int i = 0; i < 4; ++i)
    #pragma unroll
    for (int j = 0; j < 4; ++j) acc[i][j] = f32x4{0.f, 0.f, 0.f, 0.f};

  for (int kb = 0; kb < K; kb += 64) {
    #pragma unroll
    for (int c = 0; c < 4; ++c) {
      glds16(gA0 + kb + (size_t)(c * 32) * K, lA0 + c * 32 * 64);
      glds16(gB0 + kb + (size_t)(c * 32) * K, lB0 + c * 32 * 64);
    }
    __syncthreads();
    #pragma unroll
    for (int kk = 0; kk < 2; ++kk) {
      bf16x8 af[4], bfr[4];
      #pragma unroll
      for (int i = 0; i < 4; ++i) {
        const int R = wr * 64 + i * 16 + l15;
        af[i] = *reinterpret_cast<const bf16x8*>(sA + R * 64 + (((kk * 4 + l4) ^ (R & 7)) * 8));
      }
      #pragma unroll
      for (int j = 0; j < 4; ++j) {
        const int R = wc * 64 + j * 16 + l15;
        bfr[j] = *reinterpret_cast<const bf16x8*>(sB + R * 64 + (((kk * 4 + l4) ^ (R & 7)) * 8));
      }
      #pragma unroll
      for (int i = 0; i < 4; ++i)
        #pragma unroll
        for (int j = 0; j < 4; ++j)
          acc[i][j] = __builtin_amdgcn_mfma_f32_16x16x32_bf16(af[i], bfr[j], acc[i][j], 0, 0, 0);
    }
    __syncthreads();
  }

  #pragma unroll
  for (int j = 0; j < 4; ++j) {
    const int n = bx * 128 + wc * 64 + j * 16 + l15;
    const float bj = bias[n];
    #pragma unroll
    for (int i = 0; i < 4; ++i)
      #pragma unroll
      for (int r = 0; r < 4; ++r) {
        const int m = by * 128 + wr * 64 + i * 16 + l4 * 4 + r;
        Out[(size_t)m * 1024 + n] = acc[i][j][r] + bj;
      }
  }
}

// ---------------- flash attention (causal), head-major inputs ----------------
// R10/R14-proven version (145 us). 2048 blocks, 4 waves; q-tile pair (g,63-g),
// even/odd kt split, KT=32, swapped QK^T lane-local softmax, defer-max THR=8.
__global__ __launch_bounds__(256, 3)
void k_attn(const bf16* __restrict__ Qh, const bf16* __restrict__ Kh,
            const bf16* __restrict__ Vt, bf16* __restrict__ Ao)
{
  __shared__ unsigned int smem[4608];
  const int tid = threadIdx.x;
  const int wv = tid >> 6, lane = tid & 63;
  const int l4 = lane >> 4, l15 = lane & 15;

  const int bid = blockIdx.x;
  const int xcd = bid & 7;
  const int idx = bid >> 3;
  const int g   = idx & 31;
  const int grp = idx >> 5;
  const int bh  = grp * 8 + xcd;
  const int b = bh >> 4, h = bh & 15;

  const int role = (wv + bid) & 3;
  const int qi = (role < 2) ? g : (63 - g);
  const int parity = role & 1;
  const int qbase = qi * 32;

  const bf16* Qp = Qh + (size_t)bh * 2048 * 64;
  const bf16* Kp = Kh + (size_t)bh * 2048 * 64;
  const bf16* Vp = Vt + (size_t)bh * 64 * 2048;
  bf16* Pw = (bf16*)smem + wv * (32 * 40);

  bf16x8 qa[2][2];
  #pragma unroll
  for (int i = 0; i < 2; ++i)
    #pragma unroll
    for (int kh = 0; kh < 2; ++kh)
      qa[i][kh] = *reinterpret_cast<const bf16x8*>(
          Qp + (size_t)(qbase + i * 16 + l15) * 64 + kh * 32 + l4 * 8);

  f32x4 o[2][4];
  float mr[2], lr[2];
  #pragma unroll
  for (int i = 0; i < 2; ++i) {
    #pragma unroll
    for (int jd = 0; jd < 4; ++jd) o[i][jd] = f32x4{0.f, 0.f, 0.f, 0.f};
    mr[i] = -1e30f; lr[i] = 0.f;
  }

  const int ktmax = (qbase + 31) >> 5;

  const int kt0 = (parity <= ktmax) ? parity : ktmax;
  bf16x8 kbf[2][2];
  #pragma unroll
  for (int j = 0; j < 2; ++j)
    #pragma unroll
    for (int kh = 0; kh < 2; ++kh)
      kbf[j][kh] = *reinterpret_cast<const bf16x8*>(
          Kp + (size_t)(kt0 * 32 + j * 16 + l15) * 64 + kh * 32 + l4 * 8);

  for (int kt = parity; kt <= ktmax; kt += 2) {
    const bool full = (kt * 32 + 31) <= qbase;

    f32x4 s[2][2];
    #pragma unroll
    for (int i = 0; i < 2; ++i)
      #pragma unroll
      for (int j = 0; j < 2; ++j) s[i][j] = f32x4{0.f, 0.f, 0.f, 0.f};
    #pragma unroll
    for (int j = 0; j < 2; ++j)
      #pragma unroll
      for (int i = 0; i < 2; ++i) {
        s[i][j] = __builtin_amdgcn_mfma_f32_16x16x32_bf16(kbf[j][0], qa[i][0], s[i][j], 0, 0, 0);
        s[i][j] = __builtin_amdgcn_mfma_f32_16x16x32_bf16(kbf[j][1], qa[i][1], s[i][j], 0, 0, 0);
      }

    bf16x8 vbf[4];
    #pragma unroll
    for (int jd = 0; jd < 4; ++jd)
      vbf[jd] = *reinterpret_cast<const bf16x8*>(
          Vp + (size_t)(jd * 16 + l15) * 2048 + kt * 32 + l4 * 8);

    #pragma unroll
    for (int i = 0; i < 2; ++i) {
      const int q = qbase + i * 16 + l15;
      #pragma unroll
      for (int j = 0; j < 2; ++j)
        #pragma unroll
        for (int r = 0; r < 4; ++r) {
          float v = s[i][j][r];
          if (!full) {
            const int kk = kt * 32 + j * 16 + l4 * 4 + r;
            if (kk > q) v = -1e30f;
          }
          s[i][j][r] = v;
        }
    }

    #pragma unroll
    for (int i = 0; i < 2; ++i) {
      float mx = s[i][0][0];
      #pragma unroll
      for (int j = 0; j < 2; ++j)
        #pragma unroll
        for (int r = 0; r < 4; ++r)
          if (j + r > 0) mx = fmaxf(mx, s[i][j][r]);
      mx = fmaxf(mx, __shfl_xor(mx, 16));
      mx = fmaxf(mx, __shfl_xor(mx, 32));
      if (__any(mx > mr[i] + 8.f)) {
        const float mn = fmaxf(mr[i], mx);
        const float al = ex2(mr[i] - mn);
        mr[i] = mn;
        lr[i] *= al;
        float albc[4];
        #pragma unroll
        for (int r = 0; r < 4; ++r) albc[r] = __shfl(al, l4 * 4 + r);
        #pragma unroll
        for (int jd = 0; jd < 4; ++jd)
          #pragma unroll
          for (int r = 0; r < 4; ++r) o[i][jd][r] *= albc[r];
      }
      float ps = 0.f;
      #pragma unroll
      for (int j = 0; j < 2; ++j) {
        const float p0 = ex2(s[i][j][0] - mr[i]);
        const float p1 = ex2(s[i][j][1] - mr[i]);
        const float p2 = ex2(s[i][j][2] - mr[i]);
        const float p3 = ex2(s[i][j][3] - mr[i]);
        ps += (p0 + p1) + (p2 + p3);
        const unsigned int u0 = (unsigned int)f2b(p0) | ((unsigned int)f2b(p1) << 16);
        const unsigned int u1 = (unsigned int)f2b(p2) | ((unsigned int)f2b(p3) << 16);
        *reinterpret_cast<uint2*>(Pw + (i * 16 + l15) * 40 + j * 16 + l4 * 4) =
            make_uint2(u0, u1);
      }
      ps += __shfl_xor(ps, 16);
      ps += __shfl_xor(ps, 32);
      lr[i] += ps;
    }

    const int ktn = (kt + 2 <= ktmax) ? (kt + 2) : ktmax;
    #pragma unroll
    for (int j = 0; j < 2; ++j)
      #pragma unroll
      for (int kh = 0; kh < 2; ++kh)
        kbf[j][kh] = *reinterpret_cast<const bf16x8*>(
            Kp + (size_t)(ktn * 32 + j * 16 + l15) * 64 + kh * 32 + l4 * 8);

    bf16x8 pa[2];
    #pragma unroll
    for (int i = 0; i < 2; ++i)
      pa[i] = *reinterpret_cast<const bf16x8*>(Pw + (i * 16 + l15) * 40 + l4 * 8);
    #pragma unroll
    for (int jd = 0; jd < 4; ++jd)
      #pragma unroll
      for (int i = 0; i < 2; ++i)
        o[i][jd] = __builtin_amdgcn_mfma_f32_16x16x32_bf16(pa[i], vbf[jd], o[i][jd], 0, 0, 0);
  }

  float mrv[2][4], lrv[2][4];
  #pragma unroll
  for (int i = 0; i < 2; ++i)
    #pragma unroll
    for (int r = 0; r < 4; ++r) {
      mrv[i][r] = __shfl(mr[i], l4 * 4 + r);
      lrv[i][r] = __shfl(lr[i], l4 * 4 + r);
    }

  __syncthreads();
  unsigned int* reg0 = smem;
  unsigned int* reg1 = smem + 64 * 33;
  if (parity == 1) {
    unsigned int* p = ((role == 1) ? reg0 : reg1) + lane * 33;
    #pragma unroll
    for (int i = 0; i < 2; ++i)
      #pragma unroll
      for (int r = 0; r < 4; ++r) {
        p[i * 4 + r]     = __builtin_bit_cast(unsigned int, mrv[i][r]);
        p[8 + i * 4 + r] = __builtin_bit_cast(unsigned int, lrv[i][r]);
      }
    #pragma unroll
    for (int i = 0; i < 2; ++i)
      #pragma unroll
      for (int jd = 0; jd < 4; ++jd)
        #pragma unroll
        for (int rp = 0; rp < 2; ++rp) {
          unsigned int lo = f2b(o[i][jd][2 * rp]);
          unsigned int hi = f2b(o[i][jd][2 * rp + 1]);
          p[16 + (i * 4 + jd) * 2 + rp] = lo | (hi << 16);
        }
  }
  __syncthreads();
  if (parity == 0) {
    const unsigned int* p = ((role == 0) ? reg0 : reg1) + lane * 33;
    #pragma unroll
    for (int i = 0; i < 2; ++i)
      #pragma unroll
      for (int r = 0; r < 4; ++r) {
        const float m1 = __builtin_bit_cast(float, p[i * 4 + r]);
        const float l1 = __builtin_bit_cast(float, p[8 + i * 4 + r]);
        const float mm = fmaxf(mrv[i][r], m1);
        const float a0 = ex2(mrv[i][r] - mm);
        const float a1 = ex2(m1 - mm);
        const float inv = 1.f / (lrv[i][r] * a0 + l1 * a1);
        const int q = qbase + i * 16 + l4 * 4 + r;
        #pragma unroll
        for (int jd = 0; jd < 4; ++jd) {
          const unsigned int u = p[16 + (i * 4 + jd) * 2 + (r >> 1)];
          const float o1 = b2f((r & 1) ? (u >> 16) : (u & 0xffffu));
          const float val = (o[i][jd][r] * a0 + o1 * a1) * inv;
          Ao[(size_t)(b * 2048 + q) * 1024 + h * 64 + jd * 16 + l15] = __float2bfloat16(val);
        }
      }
  }
}

extern "C" void kernel_launch(void* const* d_in, const int* in_sizes, int n_in,
                              void* d_out, int out_size, void* d_ws, size_t ws_size,
                              hipStream_t stream)
{
  const float* x     = (const float*)d_in[0];
  const float* W_qkv = (const float*)d_in[1];
  const float* b_qkv = (const float*)d_in[2];
  const float* W_fc  = (const float*)d_in[3];
  const float* b_fc  = (const float*)d_in[4];
  float* out = (float*)d_out;

  char* ws = (char*)d_ws;
  bf16* x_bf = (bf16*)ws;  ws += (size_t)8192 * 1024 * 2;            // 16 MB
  bf16* Wqt  = (bf16*)ws;  ws += (size_t)3072 * 1024 * 2;            //  6 MB
  bf16* Wft  = (bf16*)ws;  ws += (size_t)1024 * 1024 * 2;            //  2 MB
  bf16* Qh   = (bf16*)ws;  ws += (size_t)4 * 16 * 2048 * 64 * 2;     // 16 MB
  bf16* Kh   = (bf16*)ws;  ws += (size_t)4 * 16 * 2048 * 64 * 2;     // 16 MB
  bf16* Vt   = (bf16*)ws;  ws += (size_t)4 * 16 * 64 * 2048 * 2;     // 16 MB
  bf16* Ao   = (bf16*)ws;  ws += (size_t)8192 * 1024 * 2;            // 16 MB  (total 88 MB)

  // allow 112KB dynamic LDS for the 8-phase GEMM (idempotent; ignore error)
  (void)hipFuncSetAttribute((const void*)k_gemm2,
                            hipFuncAttributeMaxDynamicSharedMemorySize, 114688);

  k_convert<<<8192, 256, 0, stream>>>(x, (unsigned short*)x_bf, 8192 * 1024 / 4);
  k_transpose<<<dim3(3072 / 32, 1024 / 32), dim3(32, 8), 0, stream>>>(W_qkv, Wqt, 1024, 3072);
  k_transpose<<<dim3(1024 / 32, 1024 / 32), dim3(32, 8), 0, stream>>>(W_fc, Wft, 1024, 1024);
  k_gemm2<<<512, 512, 114688, stream>>>(x_bf, Wqt, b_qkv, Qh, Kh, Vt);
  k_attn<<<2048, 256, 0, stream>>>(Qh, Kh, Vt, Ao);
  k_gemm_fc<<<dim3(8, 64), 256, 0, stream>>>(Ao, Wft, b_fc, out);
}

// Round 18
// 262.369 us; speedup vs baseline: 1.0242x; 1.0041x over previous
//
#include <hip/hip_runtime.h>
#include <hip/hip_bf16.h>

typedef __hip_bfloat16 bf16;
typedef short bf16x8 __attribute__((ext_vector_type(8)));
typedef float f32x4 __attribute__((ext_vector_type(4)));

// B=4, T=2048, D=1024, H=16, HD=64

static __device__ __forceinline__ void glds16(const bf16* g, bf16* l) {
  __builtin_amdgcn_global_load_lds(
      (const __attribute__((address_space(1))) void*)g,
      (__attribute__((address_space(3))) void*)l, 16, 0, 0);
}

static __device__ __forceinline__ unsigned short f2b(float f) {
  return __builtin_bit_cast(unsigned short, __float2bfloat16(f));
}
static __device__ __forceinline__ float b2f(unsigned int u16bits) {
  return __builtin_bit_cast(float, u16bits << 16);
}
static __device__ __forceinline__ float ex2(float x) {
  return __builtin_amdgcn_exp2f(x);
}

// ---------------- fp32 -> bf16 convert, 4 elems/thread ----------------
__global__ void k_convert(const float* __restrict__ in, unsigned short* __restrict__ out, int n4) {
  int i = blockIdx.x * 256 + threadIdx.x;
  if (i >= n4) return;
  float4 v = reinterpret_cast<const float4*>(in)[i];
  ushort4 o;
  o.x = f2b(v.x); o.y = f2b(v.y); o.z = f2b(v.z); o.w = f2b(v.w);
  reinterpret_cast<ushort4*>(out)[i] = o;
}

// ---------------- transpose R x C fp32  ->  C x R bf16 ----------------
__global__ void k_transpose(const float* __restrict__ in, bf16* __restrict__ out, int R, int C) {
  __shared__ float t[32][33];
  int c0 = blockIdx.x * 32, r0 = blockIdx.y * 32;
  int tx = threadIdx.x, ty = threadIdx.y;  // block (32,8)
  #pragma unroll
  for (int j = 0; j < 32; j += 8)
    t[ty + j][tx] = in[(size_t)(r0 + ty + j) * C + c0 + tx];
  __syncthreads();
  #pragma unroll
  for (int j = 0; j < 32; j += 8)
    out[(size_t)(c0 + ty + j) * R + r0 + tx] = __float2bfloat16(t[tx][ty + j]);
}

// ========= QKV GEMM: 256x192 tile, BK=64, 8-phase counted-vmcnt (R17) =========
__global__ __launch_bounds__(512, 1)
void k_gemm2(const bf16* __restrict__ A, const bf16* __restrict__ Bt,
             const float* __restrict__ bias,
             bf16* __restrict__ Qh, bf16* __restrict__ Kh, bf16* __restrict__ Vt)
{
  constexpr int K = 1024, NT = 16;     // K / 64
  extern __shared__ bf16 sm[];
  #define BUFA(bb) (sm + (bb) * 28672)
  #define BUFB(bb) (sm + (bb) * 28672 + 16384)

  const int tid = threadIdx.x;
  const int wv = tid >> 6, lane = tid & 63;
  const int wr = wv >> 2, wc = wv & 3;
  const int l4 = lane >> 4, l15 = lane & 15;

  // XCD swizzle: 512 blocks (64/XCD), bijective since 512 % 8 == 0
  const int flat = blockIdx.x;
  const int swz = (flat & 7) * 64 + (flat >> 3);
  const int bx = swz % 16;             // N blocks (3072/192)
  const int by = swz / 16;             // M blocks (8192/256)

  // staging: one glds call = 8 waves x 8 rows = 64 rows x 64 cols
  const int srow = lane >> 3;          // 0..7
  const int sgran = (lane & 7) ^ srow; // pre-swizzled source granule (row&7 == srow)
  const bf16* gA = A  + (size_t)(by * 256 + wv * 8 + srow) * K + sgran * 8;
  const bf16* gB = Bt + (size_t)(bx * 192 + wv * 8 + srow) * K + sgran * 8;

  f32x4 acc[8][3];
  #pragma unroll
  for (int i = 0; i < 8; ++i)
    #pragma unroll
    for (int j = 0; j < 3; ++j) acc[i][j] = f32x4{0.f, 0.f, 0.f, 0.f};

  #define STAGE_A(t, c, bb) glds16(gA + (size_t)((c) * 64) * K + (t) * 64, BUFA(bb) + ((c) * 64 + wv * 8) * 64)
  #define STAGE_B(t, c, bb) glds16(gB + (size_t)((c) * 64) * K + (t) * 64, BUFB(bb) + ((c) * 64 + wv * 8) * 64)

  // prologue: tile0 -> buf0 (A4+B3=7), tile1 -> buf1 (B3 + A c0,c2 = 5)
  #pragma unroll
  for (int c = 0; c < 4; ++c) STAGE_A(0, c, 0);
  #pragma unroll
  for (int c = 0; c < 3; ++c) STAGE_B(0, c, 0);
  #pragma unroll
  for (int c = 0; c < 3; ++c) STAGE_B(1, c, 1);
  STAGE_A(1, 0, 1);
  STAGE_A(1, 2, 1);
  asm volatile("s_waitcnt vmcnt(5)");
  __builtin_amdgcn_sched_barrier(0);
  __builtin_amdgcn_s_barrier();
  __builtin_amdgcn_sched_barrier(0);

  for (int h = 0; h < NT; ++h) {
    const int b = h & 1;
    bf16x8 bfr[3][2];
    #pragma unroll
    for (int p = 0; p < 4; ++p) {
      // ---- ds_read register subtile ----
      if (p == 0) {
        #pragma unroll
        for (int j = 0; j < 3; ++j)
          #pragma unroll
          for (int kh = 0; kh < 2; ++kh) {
            const int R = wc * 48 + j * 16 + l15;
            bfr[j][kh] = *reinterpret_cast<const bf16x8*>(
                BUFB(b) + R * 64 + (((kh * 4 + l4) ^ (R & 7)) * 8));
          }
      }
      bf16x8 af[2][2];
      #pragma unroll
      for (int ii = 0; ii < 2; ++ii)
        #pragma unroll
        for (int kh = 0; kh < 2; ++kh) {
          const int R = wr * 128 + p * 32 + ii * 16 + l15;
          af[ii][kh] = *reinterpret_cast<const bf16x8*>(
              BUFA(b) + R * 64 + (((kh * 4 + l4) ^ (R & 7)) * 8));
        }
      // ---- stage calls into dead regions ----
      if (p == 0) { if (h + 1 < NT) { STAGE_A(h + 1, 1, b ^ 1); STAGE_A(h + 1, 3, b ^ 1); } }
      if (p == 1) { if (h + 2 < NT) { STAGE_B(h + 2, 0, b);     STAGE_B(h + 2, 1, b);     } }
      if (p == 2) { if (h + 2 < NT) { STAGE_B(h + 2, 2, b);     } }
      if (p == 3) { if (h + 2 < NT) { STAGE_A(h + 2, 0, b);     STAGE_A(h + 2, 2, b);     } }
      __builtin_amdgcn_s_barrier();
      __builtin_amdgcn_sched_barrier(0);
      asm volatile("s_waitcnt lgkmcnt(0)");
      __builtin_amdgcn_sched_barrier(0);
      __builtin_amdgcn_s_setprio(1);
      #pragma unroll
      for (int ii = 0; ii < 2; ++ii)
        #pragma unroll
        for (int j = 0; j < 3; ++j) {
          acc[p * 2 + ii][j] = __builtin_amdgcn_mfma_f32_16x16x32_bf16(af[ii][0], bfr[j][0], acc[p * 2 + ii][j], 0, 0, 0);
          acc[p * 2 + ii][j] = __builtin_amdgcn_mfma_f32_16x16x32_bf16(af[ii][1], bfr[j][1], acc[p * 2 + ii][j], 0, 0, 0);
        }
      __builtin_amdgcn_s_setprio(0);
      if (p == 3) {
        if (h < NT - 2) asm volatile("s_waitcnt vmcnt(5)");
        else            asm volatile("s_waitcnt vmcnt(0)");
        __builtin_amdgcn_sched_barrier(0);
      }
      __builtin_amdgcn_s_barrier();
      __builtin_amdgcn_sched_barrier(0);
    }
  }
  #undef STAGE_A
  #undef STAGE_B
  #undef BUFA
  #undef BUFB

  // epilogue: scatter to Qh/Kh/Vt (+bias; Q pre-scaled into exp2 domain)
  #pragma unroll
  for (int j = 0; j < 3; ++j) {
    const int n = bx * 192 + wc * 48 + j * 16 + l15;
    const float bj = bias[n];
    const int s = n >> 10;
    const int hh = (n >> 6) & 15;
    const int d = n & 63;
    #pragma unroll
    for (int i = 0; i < 8; ++i) {
      #pragma unroll
      for (int r = 0; r < 4; ++r) {
        const int m = by * 256 + wr * 128 + i * 16 + l4 * 4 + r;
        const int bb = m >> 11, t = m & 2047;
        float of = acc[i][j][r] + bj;
        if (s == 0) of *= 0.18033688f;  // 1/8 * log2(e)
        const bf16 o = __float2bfloat16(of);
        if (s == 0)      Qh[((size_t)((bb * 16 + hh) * 2048 + t)) * 64 + d] = o;
        else if (s == 1) Kh[((size_t)((bb * 16 + hh) * 2048 + t)) * 64 + d] = o;
        else             Vt[((size_t)((bb * 16 + hh) * 64 + d)) * 2048 + t] = o;
      }
    }
  }
}

// ---------------- FC GEMM (R14-proven): 128x128, BK=64, swizzled LDS ----------------
__global__ __launch_bounds__(256, 2)
void k_gemm_fc(const bf16* __restrict__ A, const bf16* __restrict__ Bt,
               const float* __restrict__ bias, float* __restrict__ Out)
{
  constexpr int K = 1024;
  __shared__ bf16 sA[128 * 64];
  __shared__ bf16 sB[128 * 64];
  const int tid = threadIdx.x;
  const int wv = tid >> 6, lane = tid & 63;
  const int wr = wv >> 1, wc = wv & 1;
  const int l4 = lane >> 4, l15 = lane & 15;

  const int nbx = gridDim.x;
  const int nwg = nbx * gridDim.y;
  const int flat = blockIdx.y * nbx + blockIdx.x;
  const int cpx = nwg >> 3;
  const int swz = (flat & 7) * cpx + (flat >> 3);
  const int bx = swz % nbx;
  const int by = swz / nbx;

  const int srow8 = lane >> 3;
  const int sgran = (lane & 7) ^ srow8;
  const bf16* gA0 = A  + (size_t)(by * 128 + wv * 8 + srow8) * K + sgran * 8;
  const bf16* gB0 = Bt + (size_t)(bx * 128 + wv * 8 + srow8) * K + sgran * 8;
  bf16* lA0 = sA + wv * 8 * 64;
  bf16* lB0 = sB + wv * 8 * 64;

  f32x4 acc[4][4];
  #pragma unroll
  for (int i = 0; i < 4; ++i)
    #pragma unroll
    for (int j = 0; j < 4; ++j) acc[i][j] = f32x4{0.f, 0.f, 0.f, 0.f};

  for (int kb = 0; kb < K; kb += 64) {
    #pragma unroll
    for (int c = 0; c < 4; ++c) {
      glds16(gA0 + kb + (size_t)(c * 32) * K, lA0 + c * 32 * 64);
      glds16(gB0 + kb + (size_t)(c * 32) * K, lB0 + c * 32 * 64);
    }
    __syncthreads();
    #pragma unroll
    for (int kk = 0; kk < 2; ++kk) {
      bf16x8 af[4], bfr[4];
      #pragma unroll
      for (int i = 0; i < 4; ++i) {
        const int R = wr * 64 + i * 16 + l15;
        af[i] = *reinterpret_cast<const bf16x8*>(sA + R * 64 + (((kk * 4 + l4) ^ (R & 7)) * 8));
      }
      #pragma unroll
      for (int j = 0; j < 4; ++j) {
        const int R = wc * 64 + j * 16 + l15;
        bfr[j] = *reinterpret_cast<const bf16x8*>(sB + R * 64 + (((kk * 4 + l4) ^ (R & 7)) * 8));
      }
      #pragma unroll
      for (int i = 0; i < 4; ++i)
        #pragma unroll
        for (int j = 0; j < 4; ++j)
          acc[i][j] = __builtin_amdgcn_mfma_f32_16x16x32_bf16(af[i], bfr[j], acc[i][j], 0, 0, 0);
    }
    __syncthreads();
  }

  #pragma unroll
  for (int j = 0; j < 4; ++j) {
    const int n = bx * 128 + wc * 64 + j * 16 + l15;
    const float bj = bias[n];
    #pragma unroll
    for (int i = 0; i < 4; ++i)
      #pragma unroll
      for (int r = 0; r < 4; ++r) {
        const int m = by * 128 + wr * 64 + i * 16 + l4 * 4 + r;
        Out[(size_t)m * 1024 + n] = acc[i][j][r] + bj;
      }
  }
}

// ---------------- flash attention (causal), head-major inputs ----------------
// R10/R14-proven structure. (256,4) this round: kernel now lives in ~120 regs
// (KT=32 + swapped softmax + defer-max shrank it from R4/R5's ~150), so the
// 128-reg budget should fit WITHOUT spill and buy a 4th resident wave/SIMD.
// Spill tripwire: WRITE_SIZE must stay ~16-25 MB (R5's failure showed 330 MB).
__global__ __launch_bounds__(256, 4)
void k_attn(const bf16* __restrict__ Qh, const bf16* __restrict__ Kh,
            const bf16* __restrict__ Vt, bf16* __restrict__ Ao)
{
  __shared__ unsigned int smem[4608];
  const int tid = threadIdx.x;
  const int wv = tid >> 6, lane = tid & 63;
  const int l4 = lane >> 4, l15 = lane & 15;

  const int bid = blockIdx.x;
  const int xcd = bid & 7;
  const int idx = bid >> 3;
  const int g   = idx & 31;
  const int grp = idx >> 5;
  const int bh  = grp * 8 + xcd;
  const int b = bh >> 4, h = bh & 15;

  const int role = (wv + bid) & 3;
  const int qi = (role < 2) ? g : (63 - g);
  const int parity = role & 1;
  const int qbase = qi * 32;

  const bf16* Qp = Qh + (size_t)bh * 2048 * 64;
  const bf16* Kp = Kh + (size_t)bh * 2048 * 64;
  const bf16* Vp = Vt + (size_t)bh * 64 * 2048;
  bf16* Pw = (bf16*)smem + wv * (32 * 40);

  bf16x8 qa[2][2];
  #pragma unroll
  for (int i = 0; i < 2; ++i)
    #pragma unroll
    for (int kh = 0; kh < 2; ++kh)
      qa[i][kh] = *reinterpret_cast<const bf16x8*>(
          Qp + (size_t)(qbase + i * 16 + l15) * 64 + kh * 32 + l4 * 8);

  f32x4 o[2][4];
  float mr[2], lr[2];
  #pragma unroll
  for (int i = 0; i < 2; ++i) {
    #pragma unroll
    for (int jd = 0; jd < 4; ++jd) o[i][jd] = f32x4{0.f, 0.f, 0.f, 0.f};
    mr[i] = -1e30f; lr[i] = 0.f;
  }

  const int ktmax = (qbase + 31) >> 5;

  const int kt0 = (parity <= ktmax) ? parity : ktmax;
  bf16x8 kbf[2][2];
  #pragma unroll
  for (int j = 0; j < 2; ++j)
    #pragma unroll
    for (int kh = 0; kh < 2; ++kh)
      kbf[j][kh] = *reinterpret_cast<const bf16x8*>(
          Kp + (size_t)(kt0 * 32 + j * 16 + l15) * 64 + kh * 32 + l4 * 8);

  for (int kt = parity; kt <= ktmax; kt += 2) {
    const bool full = (kt * 32 + 31) <= qbase;

    f32x4 s[2][2];
    #pragma unroll
    for (int i = 0; i < 2; ++i)
      #pragma unroll
      for (int j = 0; j < 2; ++j) s[i][j] = f32x4{0.f, 0.f, 0.f, 0.f};
    #pragma unroll
    for (int j = 0; j < 2; ++j)
      #pragma unroll
      for (int i = 0; i < 2; ++i) {
        s[i][j] = __builtin_amdgcn_mfma_f32_16x16x32_bf16(kbf[j][0], qa[i][0], s[i][j], 0, 0, 0);
        s[i][j] = __builtin_amdgcn_mfma_f32_16x16x32_bf16(kbf[j][1], qa[i][1], s[i][j], 0, 0, 0);
      }

    bf16x8 vbf[4];
    #pragma unroll
    for (int jd = 0; jd < 4; ++jd)
      vbf[jd] = *reinterpret_cast<const bf16x8*>(
          Vp + (size_t)(jd * 16 + l15) * 2048 + kt * 32 + l4 * 8);

    #pragma unroll
    for (int i = 0; i < 2; ++i) {
      const int q = qbase + i * 16 + l15;
      #pragma unroll
      for (int j = 0; j < 2; ++j)
        #pragma unroll
        for (int r = 0; r < 4; ++r) {
          float v = s[i][j][r];
          if (!full) {
            const int kk = kt * 32 + j * 16 + l4 * 4 + r;
            if (kk > q) v = -1e30f;
          }
          s[i][j][r] = v;
        }
    }

    #pragma unroll
    for (int i = 0; i < 2; ++i) {
      float mx = s[i][0][0];
      #pragma unroll
      for (int j = 0; j < 2; ++j)
        #pragma unroll
        for (int r = 0; r < 4; ++r)
          if (j + r > 0) mx = fmaxf(mx, s[i][j][r]);
      mx = fmaxf(mx, __shfl_xor(mx, 16));
      mx = fmaxf(mx, __shfl_xor(mx, 32));
      if (__any(mx > mr[i] + 8.f)) {
        const float mn = fmaxf(mr[i], mx);
        const float al = ex2(mr[i] - mn);
        mr[i] = mn;
        lr[i] *= al;
        float albc[4];
        #pragma unroll
        for (int r = 0; r < 4; ++r) albc[r] = __shfl(al, l4 * 4 + r);
        #pragma unroll
        for (int jd = 0; jd < 4; ++jd)
          #pragma unroll
          for (int r = 0; r < 4; ++r) o[i][jd][r] *= albc[r];
      }
      float ps = 0.f;
      #pragma unroll
      for (int j = 0; j < 2; ++j) {
        const float p0 = ex2(s[i][j][0] - mr[i]);
        const float p1 = ex2(s[i][j][1] - mr[i]);
        const float p2 = ex2(s[i][j][2] - mr[i]);
        const float p3 = ex2(s[i][j][3] - mr[i]);
        ps += (p0 + p1) + (p2 + p3);
        const unsigned int u0 = (unsigned int)f2b(p0) | ((unsigned int)f2b(p1) << 16);
        const unsigned int u1 = (unsigned int)f2b(p2) | ((unsigned int)f2b(p3) << 16);
        *reinterpret_cast<uint2*>(Pw + (i * 16 + l15) * 40 + j * 16 + l4 * 4) =
            make_uint2(u0, u1);
      }
      ps += __shfl_xor(ps, 16);
      ps += __shfl_xor(ps, 32);
      lr[i] += ps;
    }

    const int ktn = (kt + 2 <= ktmax) ? (kt + 2) : ktmax;
    #pragma unroll
    for (int j = 0; j < 2; ++j)
      #pragma unroll
      for (int kh = 0; kh < 2; ++kh)
        kbf[j][kh] = *reinterpret_cast<const bf16x8*>(
            Kp + (size_t)(ktn * 32 + j * 16 + l15) * 64 + kh * 32 + l4 * 8);

    bf16x8 pa[2];
    #pragma unroll
    for (int i = 0; i < 2; ++i)
      pa[i] = *reinterpret_cast<const bf16x8*>(Pw + (i * 16 + l15) * 40 + l4 * 8);
    #pragma unroll
    for (int jd = 0; jd < 4; ++jd)
      #pragma unroll
      for (int i = 0; i < 2; ++i)
        o[i][jd] = __builtin_amdgcn_mfma_f32_16x16x32_bf16(pa[i], vbf[jd], o[i][jd], 0, 0, 0);
  }

  float mrv[2][4], lrv[2][4];
  #pragma unroll
  for (int i = 0; i < 2; ++i)
    #pragma unroll
    for (int r = 0; r < 4; ++r) {
      mrv[i][r] = __shfl(mr[i], l4 * 4 + r);
      lrv[i][r] = __shfl(lr[i], l4 * 4 + r);
    }

  __syncthreads();
  unsigned int* reg0 = smem;
  unsigned int* reg1 = smem + 64 * 33;
  if (parity == 1) {
    unsigned int* p = ((role == 1) ? reg0 : reg1) + lane * 33;
    #pragma unroll
    for (int i = 0; i < 2; ++i)
      #pragma unroll
      for (int r = 0; r < 4; ++r) {
        p[i * 4 + r]     = __builtin_bit_cast(unsigned int, mrv[i][r]);
        p[8 + i * 4 + r] = __builtin_bit_cast(unsigned int, lrv[i][r]);
      }
    #pragma unroll
    for (int i = 0; i < 2; ++i)
      #pragma unroll
      for (int jd = 0; jd < 4; ++jd)
        #pragma unroll
        for (int rp = 0; rp < 2; ++rp) {
          unsigned int lo = f2b(o[i][jd][2 * rp]);
          unsigned int hi = f2b(o[i][jd][2 * rp + 1]);
          p[16 + (i * 4 + jd) * 2 + rp] = lo | (hi << 16);
        }
  }
  __syncthreads();
  if (parity == 0) {
    const unsigned int* p = ((role == 0) ? reg0 : reg1) + lane * 33;
    #pragma unroll
    for (int i = 0; i < 2; ++i)
      #pragma unroll
      for (int r = 0; r < 4; ++r) {
        const float m1 = __builtin_bit_cast(float, p[i * 4 + r]);
        const float l1 = __builtin_bit_cast(float, p[8 + i * 4 + r]);
        const float mm = fmaxf(mrv[i][r], m1);
        const float a0 = ex2(mrv[i][r] - mm);
        const float a1 = ex2(m1 - mm);
        const float inv = 1.f / (lrv[i][r] * a0 + l1 * a1);
        const int q = qbase + i * 16 + l4 * 4 + r;
        #pragma unroll
        for (int jd = 0; jd < 4; ++jd) {
          const unsigned int u = p[16 + (i * 4 + jd) * 2 + (r >> 1)];
          const float o1 = b2f((r & 1) ? (u >> 16) : (u & 0xffffu));
          const float val = (o[i][jd][r] * a0 + o1 * a1) * inv;
          Ao[(size_t)(b * 2048 + q) * 1024 + h * 64 + jd * 16 + l15] = __float2bfloat16(val);
        }
      }
  }
}

extern "C" void kernel_launch(void* const* d_in, const int* in_sizes, int n_in,
                              void* d_out, int out_size, void* d_ws, size_t ws_size,
                              hipStream_t stream)
{
  const float* x     = (const float*)d_in[0];
  const float* W_qkv = (const float*)d_in[1];
  const float* b_qkv = (const float*)d_in[2];
  const float* W_fc  = (const float*)d_in[3];
  const float* b_fc  = (const float*)d_in[4];
  float* out = (float*)d_out;

  char* ws = (char*)d_ws;
  bf16* x_bf = (bf16*)ws;  ws += (size_t)8192 * 1024 * 2;            // 16 MB
  bf16* Wqt  = (bf16*)ws;  ws += (size_t)3072 * 1024 * 2;            //  6 MB
  bf16* Wft  = (bf16*)ws;  ws += (size_t)1024 * 1024 * 2;            //  2 MB
  bf16* Qh   = (bf16*)ws;  ws += (size_t)4 * 16 * 2048 * 64 * 2;     // 16 MB
  bf16* Kh   = (bf16*)ws;  ws += (size_t)4 * 16 * 2048 * 64 * 2;     // 16 MB
  bf16* Vt   = (bf16*)ws;  ws += (size_t)4 * 16 * 64 * 2048 * 2;     // 16 MB
  bf16* Ao   = (bf16*)ws;  ws += (size_t)8192 * 1024 * 2;            // 16 MB  (total 88 MB)

  // allow 112KB dynamic LDS for the 8-phase GEMM (idempotent; ignore error)
  (void)hipFuncSetAttribute((const void*)k_gemm2,
                            hipFuncAttributeMaxDynamicSharedMemorySize, 114688);

  k_convert<<<8192, 256, 0, stream>>>(x, (unsigned short*)x_bf, 8192 * 1024 / 4);
  k_transpose<<<dim3(3072 / 32, 1024 / 32), dim3(32, 8), 0, stream>>>(W_qkv, Wqt, 1024, 3072);
  k_transpose<<<dim3(1024 / 32, 1024 / 32), dim3(32, 8), 0, stream>>>(W_fc, Wft, 1024, 1024);
  k_gemm2<<<512, 512, 114688, stream>>>(x_bf, Wqt, b_qkv, Qh, Kh, Vt);
  k_attn<<<2048, 256, 0, stream>>>(Qh, Kh, Vt, Ao);
  k_gemm_fc<<<dim3(8, 64), 256, 0, stream>>>(Ao, Wft, b_fc, out);
}